// Round 1
// baseline (138.767 us; speedup 1.0000x reference)
//
#include <hip/hip_runtime.h>
#include <math.h>

#define T_ 16
#define B_ 16
#define C_ 8
#define H_ 128
#define W_ 128
#define HW_ (H_*W_)
#define CHW_ (C_*HW_)
#define NSLICE 4
#define ROWS_PER_SLICE (H_/NSLICE)   // 32
#define NV 19                        // 0..7 sumc, 8..15 maxc, 16 dsum, 17 m1, 18 m2

__device__ __forceinline__ float wave_sum(float v){
    #pragma unroll
    for (int o=32;o>0;o>>=1) v += __shfl_down(v,o,64);
    return v;
}
__device__ __forceinline__ float wave_max(float v){
    #pragma unroll
    for (int o=32;o>0;o>>=1) v = fmaxf(v,__shfl_down(v,o,64));
    return v;
}

// ---------------- K1: per-(t,b) row-slice statistics ----------------
__global__ __launch_bounds__(128) void stats_kernel(
    const float* __restrict__ events, float* __restrict__ partials)
{
    int blk = blockIdx.x;
    int s  = blk % NSLICE;
    int tb = blk / NSLICE;
    int t  = tb / B_;
    int w  = threadIdx.x;           // 0..127 (column)
    int h0 = s * ROWS_PER_SLICE;
    const float* frame = events + (size_t)tb * CHW_;
    const float* prev  = frame - (size_t)B_ * CHW_;   // only deref'd when t>0

    __shared__ float yb[ROWS_PER_SLICE+2][W_];        // y = sum over channels

    float maxc[C_], sumc[C_];
    #pragma unroll
    for (int c=0;c<C_;c++){ maxc[c] = -INFINITY; sumc[c] = 0.f; }
    float dsum=0.f, m1=0.f, m2=0.f;
    float cntw = (w==0 || w==W_-1) ? 2.f : 3.f;

    // phase 1: load rows h0-1 .. h0+32, build y rows, accumulate own-row stats
    for (int r=0; r<ROWS_PER_SLICE+2; ++r){
        int gh = h0 - 1 + r;
        float y = 0.f;
        if (gh >= 0 && gh < H_){
            bool own = (r>=1 && r<=ROWS_PER_SLICE);
            float xv[C_];
            #pragma unroll
            for (int c=0;c<C_;c++){
                float x = frame[c*HW_ + gh*W_ + w];
                xv[c] = x; y += x;
            }
            if (own){
                float ysq = 0.f;
                #pragma unroll
                for (int c=0;c<C_;c++){
                    float x = xv[c];
                    ysq += x*x;
                    maxc[c] = fmaxf(maxc[c], x);
                    sumc[c] += x;
                }
                float cnth = (gh==0 || gh==H_-1) ? 2.f : 3.f;
                m2 += ysq * cnth * cntw;     // sum(s2) contribution
                if (t > 0){
                    #pragma unroll
                    for (int c=0;c<C_;c++)
                        dsum += fabsf(xv[c] - prev[c*HW_ + gh*W_ + w]);
                }
            }
        }
        yb[r][w] = y;
    }
    __syncthreads();

    // phase 2: s1 = 3x3 box of y (zero padded), accumulate sum(s1^2)
    for (int r=1; r<=ROWS_PER_SLICE; ++r){
        float s1 = 0.f;
        #pragma unroll
        for (int dr=-1; dr<=1; ++dr){
            const float* row = yb[r+dr];
            float v = row[w];
            if (w>0)      v += row[w-1];
            if (w<W_-1)   v += row[w+1];
            s1 += v;
        }
        m1 += s1*s1;
    }

    // block reduce 19 quantities (2 waves)
    float vals[NV];
    #pragma unroll
    for (int c=0;c<C_;c++){ vals[c]=sumc[c]; vals[8+c]=maxc[c]; }
    vals[16]=dsum; vals[17]=m1; vals[18]=m2;

    __shared__ float red[2][NV];
    int lane = w & 63, wv = w >> 6;
    #pragma unroll
    for (int i=0;i<NV;i++){
        float r = (i>=8 && i<16) ? wave_max(vals[i]) : wave_sum(vals[i]);
        if (lane==0) red[wv][i] = r;
    }
    __syncthreads();
    if (w < NV){
        float a = red[0][w], b = red[1][w];
        float r = (w>=8 && w<16) ? fmaxf(a,b) : (a+b);
        partials[((size_t)tb*NSLICE + s)*NV + w] = r;
    }
}

// ---------------- K2: combine partials -> beta[t,b,c], thr[t,b] ----------------
__global__ __launch_bounds__(64) void combine_kernel(
    const float* __restrict__ partials,
    const float* __restrict__ att_w1,   // (1,16) row-major
    const float* __restrict__ att_w2,   // (8,1)
    const float* __restrict__ dwp, const float* __restrict__ twp,
    const float* __restrict__ mwp,
    float* __restrict__ beta_out, float* __restrict__ thr_out)
{
    int tb = blockIdx.x;
    int t  = tb / B_;
    int i  = threadIdx.x;
    __shared__ float v[NV];
    if (i < NV){
        const float* p = partials + (size_t)tb*NSLICE*NV;
        float a = p[i], b = p[NV+i], c = p[2*NV+i], d = p[3*NV+i];
        v[i] = (i>=8 && i<16) ? fmaxf(fmaxf(a,b),fmaxf(c,d)) : (a+b+c+d);
    }
    __syncthreads();
    if (i == 0){
        // pooled = [mx(8), av(8)];  h = relu(pooled . att_w1)
        float h1 = 0.f;
        for (int c=0;c<C_;c++) h1 += v[8+c] * att_w1[c];             // mx
        for (int c=0;c<C_;c++) h1 += (v[c]/(float)HW_) * att_w1[C_+c]; // av
        h1 = fmaxf(h1, 0.f);
        float total = 0.f;
        for (int c=0;c<C_;c++) total += v[c];
        float density  = total / (float)CHW_;
        float temporal = (t==0) ? 0.f : v[16] / (float)CHW_;
        float motion   = (v[18] - v[17]/72.f) / 71.f / (float)HW_;
        float z = dwp[0]*density + twp[0]*temporal + mwp[0]*motion;
        float adj = 2.f / (1.f + expf(-z));
        thr_out[tb] = 1.f + adj;
        for (int c=0;c<C_;c++){
            float sg = 1.f / (1.f + expf(-(h1 * att_w2[c])));
            beta_out[tb*C_ + c] = 0.5f + 0.45f*sg;
        }
    }
}

// ---------------- K3: depthwise conv + sequential LIF scan ----------------
__global__ __launch_bounds__(256) void lif_kernel(
    const float* __restrict__ events,
    const float* __restrict__ conv_w,   // (C,1,3,3)
    const float* __restrict__ beta,     // [T*B*C]
    const float* __restrict__ thr,      // [T*B]
    float* __restrict__ out)
{
    int bid  = blockIdx.x;
    int hblk = bid % (H_/16);           // 0..7
    int bc   = bid / (H_/16);           // 0..127
    int b = bc / C_, c = bc % C_;
    int h0 = hblk * 16;
    int tid = threadIdx.x;
    int w   = tid % W_;
    int r0  = (tid / W_) * 8;           // 0 or 8

    float wk[9];
    #pragma unroll
    for (int k=0;k<9;k++) wk[k] = conv_w[c*9 + k];

    __shared__ float ld[18][132];       // rows h0-1..h0+16, cols -1..128 (at +1 offset)

    float v[8];
    #pragma unroll
    for (int i=0;i<8;i++) v[i] = 0.f;

    for (int t=0;t<T_;++t){
        const float* frame = events + ((size_t)(t*B_+b)*C_ + c)*HW_;
        for (int i = tid; i < 18*130; i += 256){
            int rr = i / 130, cc = i % 130;
            int gh = h0 - 1 + rr, gw = cc - 1;
            float val = 0.f;
            if (gh>=0 && gh<H_ && gw>=0 && gw<W_) val = frame[gh*W_+gw];
            ld[rr][cc] = val;
        }
        __syncthreads();

        float bv = beta[(t*B_+b)*C_ + c];
        float th = thr[t*B_ + b];
        float* op = out + ((size_t)(t*B_+b)*C_ + c)*HW_;

        #pragma unroll
        for (int i=0;i<8;i++){
            int r  = r0 + i;
            int lr = r + 1, lc = w + 1;
            float wi =
                wk[0]*ld[lr-1][lc-1] + wk[1]*ld[lr-1][lc] + wk[2]*ld[lr-1][lc+1] +
                wk[3]*ld[lr  ][lc-1] + wk[4]*ld[lr  ][lc] + wk[5]*ld[lr  ][lc+1] +
                wk[6]*ld[lr+1][lc-1] + wk[7]*ld[lr+1][lc] + wk[8]*ld[lr+1][lc+1];
            float vv = bv*v[i] + (1.f-bv)*wi;                       // charge
            float spike = atanf(2.f*(vv - th))*0.5f + 0.5f;         // fire (atan surrogate)
            op[(h0+r)*W_ + w] = ld[lr][lc]*spike;                   // cur * spike
            v[i] = (1.f - spike)*vv;                                // reset
        }
        __syncthreads();   // before next t overwrites ld
    }
}

extern "C" void kernel_launch(void* const* d_in, const int* in_sizes, int n_in,
                              void* d_out, int out_size, void* d_ws, size_t ws_size,
                              hipStream_t stream)
{
    const float* events = (const float*)d_in[0];
    const float* conv_w = (const float*)d_in[1];
    const float* att_w1 = (const float*)d_in[2];
    const float* att_w2 = (const float*)d_in[3];
    const float* dwp    = (const float*)d_in[4];
    const float* twp    = (const float*)d_in[5];
    const float* mwp    = (const float*)d_in[6];
    float* out = (float*)d_out;

    float* ws       = (float*)d_ws;
    float* partials = ws;                              // 256*4*19 floats
    float* beta     = ws + (size_t)T_*B_*NSLICE*NV;    // 2048 floats
    float* thr      = beta + (size_t)T_*B_*C_;         // 256 floats

    stats_kernel  <<<T_*B_*NSLICE, 128, 0, stream>>>(events, partials);
    combine_kernel<<<T_*B_,        64,  0, stream>>>(partials, att_w1, att_w2,
                                                     dwp, twp, mwp, beta, thr);
    lif_kernel    <<<B_*C_*(H_/16), 256, 0, stream>>>(events, conv_w, beta, thr, out);
}

// Round 2
// 96.125 us; speedup vs baseline: 1.4436x; 1.4436x over previous
//
#include <hip/hip_runtime.h>
#include <math.h>

#define T_ 16
#define B_ 16
#define C_ 8
#define H_ 128
#define W_ 128
#define HW_ (H_*W_)
#define CHW_ (C_*HW_)
#define NSLICE 4
#define ROWS_PER_SLICE (H_/NSLICE)   // 32
#define NV 19                        // 0..7 sumc, 8..15 maxc, 16 dsum, 17 m1, 18 m2

__device__ __forceinline__ float wave_sum(float v){
    #pragma unroll
    for (int o=32;o>0;o>>=1) v += __shfl_down(v,o,64);
    return v;
}
__device__ __forceinline__ float wave_max(float v){
    #pragma unroll
    for (int o=32;o>0;o>>=1) v = fmaxf(v,__shfl_down(v,o,64));
    return v;
}

// ---------------- K1: per-(t,b) row-slice statistics (unchanged) ----------------
__global__ __launch_bounds__(128) void stats_kernel(
    const float* __restrict__ events, float* __restrict__ partials)
{
    int blk = blockIdx.x;
    int s  = blk % NSLICE;
    int tb = blk / NSLICE;
    int t  = tb / B_;
    int w  = threadIdx.x;           // 0..127 (column)
    int h0 = s * ROWS_PER_SLICE;
    const float* frame = events + (size_t)tb * CHW_;
    const float* prev  = frame - (size_t)B_ * CHW_;   // only deref'd when t>0

    __shared__ float yb[ROWS_PER_SLICE+2][W_];        // y = sum over channels

    float maxc[C_], sumc[C_];
    #pragma unroll
    for (int c=0;c<C_;c++){ maxc[c] = -INFINITY; sumc[c] = 0.f; }
    float dsum=0.f, m1=0.f, m2=0.f;
    float cntw = (w==0 || w==W_-1) ? 2.f : 3.f;

    for (int r=0; r<ROWS_PER_SLICE+2; ++r){
        int gh = h0 - 1 + r;
        float y = 0.f;
        if (gh >= 0 && gh < H_){
            bool own = (r>=1 && r<=ROWS_PER_SLICE);
            float xv[C_];
            #pragma unroll
            for (int c=0;c<C_;c++){
                float x = frame[c*HW_ + gh*W_ + w];
                xv[c] = x; y += x;
            }
            if (own){
                float ysq = 0.f;
                #pragma unroll
                for (int c=0;c<C_;c++){
                    float x = xv[c];
                    ysq += x*x;
                    maxc[c] = fmaxf(maxc[c], x);
                    sumc[c] += x;
                }
                float cnth = (gh==0 || gh==H_-1) ? 2.f : 3.f;
                m2 += ysq * cnth * cntw;
                if (t > 0){
                    #pragma unroll
                    for (int c=0;c<C_;c++)
                        dsum += fabsf(xv[c] - prev[c*HW_ + gh*W_ + w]);
                }
            }
        }
        yb[r][w] = y;
    }
    __syncthreads();

    for (int r=1; r<=ROWS_PER_SLICE; ++r){
        float s1 = 0.f;
        #pragma unroll
        for (int dr=-1; dr<=1; ++dr){
            const float* row = yb[r+dr];
            float v = row[w];
            if (w>0)      v += row[w-1];
            if (w<W_-1)   v += row[w+1];
            s1 += v;
        }
        m1 += s1*s1;
    }

    float vals[NV];
    #pragma unroll
    for (int c=0;c<C_;c++){ vals[c]=sumc[c]; vals[8+c]=maxc[c]; }
    vals[16]=dsum; vals[17]=m1; vals[18]=m2;

    __shared__ float red[2][NV];
    int lane = w & 63, wv = w >> 6;
    #pragma unroll
    for (int i=0;i<NV;i++){
        float r = (i>=8 && i<16) ? wave_max(vals[i]) : wave_sum(vals[i]);
        if (lane==0) red[wv][i] = r;
    }
    __syncthreads();
    if (w < NV){
        float a = red[0][w], b = red[1][w];
        float r = (w>=8 && w<16) ? fmaxf(a,b) : (a+b);
        partials[((size_t)tb*NSLICE + s)*NV + w] = r;
    }
}

// ---------------- K2: combine partials -> beta[t,b,c], thr[t,b] ----------------
__global__ __launch_bounds__(64) void combine_kernel(
    const float* __restrict__ partials,
    const float* __restrict__ att_w1,   // (1,16) row-major
    const float* __restrict__ att_w2,   // (8,1)
    const float* __restrict__ dwp, const float* __restrict__ twp,
    const float* __restrict__ mwp,
    float* __restrict__ beta_out, float* __restrict__ thr_out,
    float* __restrict__ zeropad)
{
    int tb = blockIdx.x;
    int t  = tb / B_;
    int i  = threadIdx.x;
    if (tb == 0 && i < 16) zeropad[i] = 0.f;   // 64B zero region for lif halo loads
    __shared__ float v[NV];
    if (i < NV){
        const float* p = partials + (size_t)tb*NSLICE*NV;
        float a = p[i], b = p[NV+i], c = p[2*NV+i], d = p[3*NV+i];
        v[i] = (i>=8 && i<16) ? fmaxf(fmaxf(a,b),fmaxf(c,d)) : (a+b+c+d);
    }
    __syncthreads();
    if (i == 0){
        float h1 = 0.f;
        for (int c=0;c<C_;c++) h1 += v[8+c] * att_w1[c];
        for (int c=0;c<C_;c++) h1 += (v[c]/(float)HW_) * att_w1[C_+c];
        h1 = fmaxf(h1, 0.f);
        float total = 0.f;
        for (int c=0;c<C_;c++) total += v[c];
        float density  = total / (float)CHW_;
        float temporal = (t==0) ? 0.f : v[16] / (float)CHW_;
        float motion   = (v[18] - v[17]/72.f) / 71.f / (float)HW_;
        float z = dwp[0]*density + twp[0]*temporal + mwp[0]*motion;
        float adj = 2.f / (1.f + expf(-z));
        thr_out[tb] = 1.f + adj;
        for (int c=0;c<C_;c++){
            float sg = 1.f / (1.f + expf(-(h1 * att_w2[c])));
            beta_out[tb*C_ + c] = 0.5f + 0.45f*sg;
        }
    }
}

// ---------------- K3: depthwise conv + sequential LIF scan ----------------
// 8 output rows per block, grid = B*C*16 = 2048 blocks, 256 threads.
// Double-buffered LDS, global_load_lds(16B) staging, 1 barrier per t.

__device__ __forceinline__ void gload16(const float* src, float* lds_dst){
    __builtin_amdgcn_global_load_lds(
        (const __attribute__((address_space(1))) unsigned int*)src,
        (__attribute__((address_space(3))) unsigned int*)lds_dst, 16, 0, 0);
}

__device__ __forceinline__ float fast_atan(float x){
    float ax = fabsf(x);
    bool inv = ax > 1.f;
    float z  = inv ? __builtin_amdgcn_rcpf(ax) : ax;
    float z2 = z*z;
    float p = -0.0117212f;
    p = fmaf(p, z2,  0.05265332f);
    p = fmaf(p, z2, -0.11643287f);
    p = fmaf(p, z2,  0.19354346f);
    p = fmaf(p, z2, -0.33262347f);
    p = fmaf(p, z2,  0.99997726f);
    p = p * z;
    float r = inv ? (1.57079632679f - p) : p;
    return copysignf(r, x);
}

#define SROWS 10   // staged rows: h0-1 .. h0+8

__global__ __launch_bounds__(256, 8) void lif_kernel(
    const float* __restrict__ events,
    const float* __restrict__ conv_w,   // (C,1,3,3)
    const float* __restrict__ beta,     // [T*B*C]
    const float* __restrict__ thr,      // [T*B]
    const float* __restrict__ zeropad,  // >=16B of zeros
    float* __restrict__ out)
{
    int bid  = blockIdx.x;
    int hblk = bid & 15;                // 16 row-blocks of 8 rows
    int bc   = bid >> 4;                // 0..127
    int b = bc >> 3, c = bc & 7;
    int h0 = hblk * 8;
    int tid = threadIdx.x;
    int wv  = tid >> 6;                 // wave id 0..3

    float wk[9];
    #pragma unroll
    for (int k=0;k<9;k++) wk[k] = conv_w[c*9 + k];

    __shared__ float lds[2][SROWS*W_];  // 2 x 10 x 128 floats = 10 KiB

    // --- staging address precompute (f4 granularity) ---
    // call A: f4 idx = tid (rows 0..7); call B (wave 0 only): f4 idx = 256+lane (rows 8..9)
    int idxA = tid,        rowA = idxA >> 5, colA = (idxA & 31) * 4;
    int idxB = 256 + tid,  rowB = idxB >> 5, colB = (idxB & 31) * 4;
    int ghA = h0 - 1 + rowA;
    int ghB = h0 - 1 + rowB;
    bool okA = (ghA >= 0) && (ghA < H_);
    bool okB = (ghB >= 0) && (ghB < H_);
    const float* baseFrame = events + ((size_t)(b * C_) + c) * HW_;  // t=0 frame
    const float* srcA0 = okA ? (baseFrame + ghA*W_ + colA) : zeropad;
    const float* srcB0 = okB ? (baseFrame + ghB*W_ + colB) : zeropad;
    const size_t tstep = (size_t)B_ * CHW_;
    size_t stepA = okA ? tstep : 0;     // zeropad src does not advance
    size_t stepB = okB ? tstep : 0;

    // --- compute mapping ---
    int w  = tid & 127;
    int rg = tid >> 7;                  // 0 or 1
    int rbase = rg * 4;                 // output rows rbase..rbase+3 within block
    int wl = (w > 0)    ? w-1 : 0;
    int wr = (w < W_-1) ? w+1 : W_-1;
    bool hasL = (w > 0), hasR = (w < W_-1);

    float v[4];
    #pragma unroll
    for (int i=0;i<4;i++) v[i] = 0.f;

    // prologue: stage t=0 into buffer 0
    gload16(srcA0, &lds[0][wv*256]);
    if (wv == 0) gload16(srcB0, &lds[0][1024]);

    const float* bp = beta + (b*C_ + c);
    const float* tp = thr + b;
    float bv = bp[0];                   // t=0 (index (0*B+b)*C+c)
    float th = tp[0];

    for (int t = 0; t < T_; ++t){
        int cur = t & 1, nxt = cur ^ 1;
        __syncthreads();   // drains prefetch(t) loads; retires compute(t-1) reads

        // issue prefetch for t+1 into the other buffer (overlaps compute)
        if (t + 1 < T_){
            gload16(srcA0 + (size_t)(t+1)*stepA, &lds[nxt][wv*256]);
            if (wv == 0) gload16(srcB0 + (size_t)(t+1)*stepB, &lds[nxt][1024]);
        }
        // prefetch next beta/thr
        float bvn = (t+1 < T_) ? bp[(size_t)(t+1)*B_*C_] : 0.f;
        float thn = (t+1 < T_) ? tp[(size_t)(t+1)*B_]    : 0.f;

        const float* L = &lds[cur][0];
        float omb = 1.f - bv;
        float* op = out + ((size_t)(t*B_+b)*C_ + c)*HW_ + h0*W_;

        // rolling 3x3: staging rows rbase .. rbase+5
        const float* row0 = L + rbase*W_;
        const float* row1 = row0 + W_;
        float la = hasL ? row0[wl] : 0.f;  float ma = row0[w];  float ra = hasR ? row0[wr] : 0.f;
        float lb = hasL ? row1[wl] : 0.f;  float mb = row1[w];  float rb = hasR ? row1[wr] : 0.f;

        #pragma unroll
        for (int i=0;i<4;i++){
            const float* rowc = L + (rbase+2+i)*W_;
            float lc = hasL ? rowc[wl] : 0.f;
            float mc = rowc[w];
            float rc = hasR ? rowc[wr] : 0.f;
            float wi = wk[0]*la + wk[1]*ma + wk[2]*ra
                     + wk[3]*lb + wk[4]*mb + wk[5]*rb
                     + wk[6]*lc + wk[7]*mc + wk[8]*rc;
            float vv = fmaf(bv, v[i], omb*wi);                 // charge
            float sp = fast_atan(2.f*(vv - th))*0.5f + 0.5f;   // fire
            op[(rbase+i)*W_ + w] = mb * sp;                    // cur * spike
            v[i] = (1.f - sp) * vv;                            // reset
            la=lb; ma=mb; ra=rb; lb=lc; mb=mc; rb=rc;
        }
        bv = bvn; th = thn;
    }
}

extern "C" void kernel_launch(void* const* d_in, const int* in_sizes, int n_in,
                              void* d_out, int out_size, void* d_ws, size_t ws_size,
                              hipStream_t stream)
{
    const float* events = (const float*)d_in[0];
    const float* conv_w = (const float*)d_in[1];
    const float* att_w1 = (const float*)d_in[2];
    const float* att_w2 = (const float*)d_in[3];
    const float* dwp    = (const float*)d_in[4];
    const float* twp    = (const float*)d_in[5];
    const float* mwp    = (const float*)d_in[6];
    float* out = (float*)d_out;

    float* ws       = (float*)d_ws;
    float* partials = ws;                              // 256*4*19 floats
    float* beta     = ws + (size_t)T_*B_*NSLICE*NV;    // 2048 floats
    float* thr      = beta + (size_t)T_*B_*C_;         // 256 floats
    float* zeropad  = thr + T_*B_;                     // 16 floats (16B-aligned)

    stats_kernel  <<<T_*B_*NSLICE, 128, 0, stream>>>(events, partials);
    combine_kernel<<<T_*B_,        64,  0, stream>>>(partials, att_w1, att_w2,
                                                     dwp, twp, mwp, beta, thr, zeropad);
    lif_kernel    <<<B_*C_*16,     256, 0, stream>>>(events, conv_w, beta, thr, zeropad, out);
}

// Round 3
// 94.116 us; speedup vs baseline: 1.4744x; 1.0213x over previous
//
#include <hip/hip_runtime.h>
#include <math.h>

#define T_ 16
#define B_ 16
#define C_ 8
#define H_ 128
#define W_ 128
#define HW_ (H_*W_)
#define CHW_ (C_*HW_)
#define NSLICE 8
#define SR (H_/NSLICE)               // 16 rows per slice
#define NV 19                        // 0..7 sumc, 8..15 maxc, 16 dsum, 17 m1, 18 m2

__device__ __forceinline__ float wave_sum(float v){
    #pragma unroll
    for (int o=32;o>0;o>>=1) v += __shfl_down(v,o,64);
    return v;
}
__device__ __forceinline__ float wave_max(float v){
    #pragma unroll
    for (int o=32;o>0;o>>=1) v = fmaxf(v,__shfl_down(v,o,64));
    return v;
}

// ---------------- K1: per-(t,b) row-slice statistics (float4, 256T, 8 slices) ----------------
__global__ __launch_bounds__(256) void stats_kernel(
    const float* __restrict__ events, float* __restrict__ partials)
{
    int blk = blockIdx.x;
    int s  = blk & (NSLICE-1);
    int tb = blk >> 3;
    int t  = tb >> 4;                 // / B_
    int h0 = s * SR;
    int tid = threadIdx.x;
    const float* frame = events + (size_t)tb * CHW_;
    const float* prev  = frame - (size_t)B_ * CHW_;   // only deref'd when t>0

    __shared__ float yb[SR+2][W_];    // y = sum over channels, rows h0-1 .. h0+SR
    __shared__ float red[4][NV];

    int cg = tid & 31;                // float4 column group
    int c0 = cg * 4;
    int r  = tid >> 5;                // 0..7 (row within pass)

    float cnt0 = (c0   == 0 || c0   == W_-1) ? 2.f : 3.f;
    float cnt1 = 3.f;
    float cnt2 = 3.f;
    float cnt3 = (c0+3 == 0 || c0+3 == W_-1) ? 2.f : 3.f;

    float sumc[C_], maxc[C_];
    #pragma unroll
    for (int c=0;c<C_;c++){ sumc[c]=0.f; maxc[c]=-INFINITY; }
    float dsum=0.f, m1=0.f, m2=0.f;

    // halo rows (y only): tid<32 -> row h0-1; tid in [32,64) -> row h0+SR
    if (tid < 64){
        int hr = (tid >> 5) ? SR : -1;
        int gh = h0 + hr;
        float y0=0.f,y1=0.f,y2=0.f,y3=0.f;
        if (gh >= 0 && gh < H_){
            const float* rp = frame + gh*W_ + (tid&31)*4;
            #pragma unroll
            for (int c=0;c<C_;c++){
                float4 x = *reinterpret_cast<const float4*>(rp + c*HW_);
                y0+=x.x; y1+=x.y; y2+=x.z; y3+=x.w;
            }
        }
        float* yp = &yb[hr+1][(tid&31)*4];
        yp[0]=y0; yp[1]=y1; yp[2]=y2; yp[3]=y3;
    }

    // main rows: 2 passes of 8 rows
    #pragma unroll 1
    for (int p=0;p<2;p++){
        int lr = r + 8*p;             // 0..15
        int gh = h0 + lr;
        const float* rp = frame + gh*W_ + c0;
        float4 xv[C_];
        #pragma unroll
        for (int c=0;c<C_;c++)
            xv[c] = *reinterpret_cast<const float4*>(rp + c*HW_);

        float y0=0.f,y1=0.f,y2=0.f,y3=0.f;
        float q0=0.f,q1=0.f,q2=0.f,q3=0.f;
        #pragma unroll
        for (int c=0;c<C_;c++){
            float4 x = xv[c];
            y0+=x.x; y1+=x.y; y2+=x.z; y3+=x.w;
            q0=fmaf(x.x,x.x,q0); q1=fmaf(x.y,x.y,q1);
            q2=fmaf(x.z,x.z,q2); q3=fmaf(x.w,x.w,q3);
            sumc[c] += (x.x+x.y)+(x.z+x.w);
            maxc[c] = fmaxf(maxc[c], fmaxf(fmaxf(x.x,x.y),fmaxf(x.z,x.w)));
        }
        float cnth = (gh==0 || gh==H_-1) ? 2.f : 3.f;
        m2 += cnth * (q0*cnt0 + q1*cnt1 + q2*cnt2 + q3*cnt3);

        if (t > 0){
            const float* pp = prev + gh*W_ + c0;
            #pragma unroll
            for (int c=0;c<C_;c++){
                float4 pv = *reinterpret_cast<const float4*>(pp + c*HW_);
                float4 x  = xv[c];
                dsum += fabsf(x.x-pv.x)+fabsf(x.y-pv.y)
                      + fabsf(x.z-pv.z)+fabsf(x.w-pv.w);
            }
        }
        float* yp = &yb[lr+1][c0];
        yp[0]=y0; yp[1]=y1; yp[2]=y2; yp[3]=y3;
    }
    __syncthreads();

    // box filter of y -> m1 += s1^2 ; thread: col w, 8 rows
    {
        int w  = tid & 127;
        int rg = tid >> 7;            // 0 or 1
        bool hasL = (w>0), hasR = (w<W_-1);
        int base = rg*8;              // local rows base..base+7  (yb rows base+1..base+8)
        const float* row;
        row = yb[base];   float a0 = row[w] + (hasL?row[w-1]:0.f) + (hasR?row[w+1]:0.f);
        row = yb[base+1]; float a1 = row[w] + (hasL?row[w-1]:0.f) + (hasR?row[w+1]:0.f);
        #pragma unroll
        for (int i=0;i<8;i++){
            row = yb[base+2+i];
            float a2 = row[w] + (hasL?row[w-1]:0.f) + (hasR?row[w+1]:0.f);
            float s1 = a0 + a1 + a2;
            m1 = fmaf(s1, s1, m1);
            a0 = a1; a1 = a2;
        }
    }

    // block reduce 19 quantities (4 waves)
    float vals[NV];
    #pragma unroll
    for (int c=0;c<C_;c++){ vals[c]=sumc[c]; vals[8+c]=maxc[c]; }
    vals[16]=dsum; vals[17]=m1; vals[18]=m2;

    int lane = tid & 63, wv = tid >> 6;
    #pragma unroll
    for (int i=0;i<NV;i++){
        float rr = (i>=8 && i<16) ? wave_max(vals[i]) : wave_sum(vals[i]);
        if (lane==0) red[wv][i] = rr;
    }
    __syncthreads();
    if (tid < NV){
        float a = red[0][tid], b = red[1][tid], c = red[2][tid], d = red[3][tid];
        float rr = (tid>=8 && tid<16) ? fmaxf(fmaxf(a,b),fmaxf(c,d)) : ((a+b)+(c+d));
        partials[((size_t)tb*NSLICE + s)*NV + tid] = rr;
    }
}

// ---------------- K2: combine partials -> beta[t,b,c], thr[t,b] ----------------
__global__ __launch_bounds__(64) void combine_kernel(
    const float* __restrict__ partials,
    const float* __restrict__ att_w1,   // (1,16) row-major
    const float* __restrict__ att_w2,   // (8,1)
    const float* __restrict__ dwp, const float* __restrict__ twp,
    const float* __restrict__ mwp,
    float* __restrict__ beta_out, float* __restrict__ thr_out,
    float* __restrict__ zeropad)
{
    int tb = blockIdx.x;
    int t  = tb / B_;
    int i  = threadIdx.x;
    if (tb == 0 && i < 16) zeropad[i] = 0.f;   // 64B zero region for lif halo loads
    __shared__ float v[NV];
    if (i < NV){
        const float* p = partials + (size_t)tb*NSLICE*NV;
        bool mx = (i>=8 && i<16);
        float acc = p[i];
        #pragma unroll
        for (int k=1;k<NSLICE;k++){
            float x = p[k*NV + i];
            acc = mx ? fmaxf(acc, x) : (acc + x);
        }
        v[i] = acc;
    }
    __syncthreads();
    if (i == 0){
        float h1 = 0.f;
        for (int c=0;c<C_;c++) h1 += v[8+c] * att_w1[c];
        for (int c=0;c<C_;c++) h1 += (v[c]/(float)HW_) * att_w1[C_+c];
        h1 = fmaxf(h1, 0.f);
        float total = 0.f;
        for (int c=0;c<C_;c++) total += v[c];
        float density  = total / (float)CHW_;
        float temporal = (t==0) ? 0.f : v[16] / (float)CHW_;
        float motion   = (v[18] - v[17]/72.f) / 71.f / (float)HW_;
        float z = dwp[0]*density + twp[0]*temporal + mwp[0]*motion;
        float adj = 2.f / (1.f + expf(-z));
        thr_out[tb] = 1.f + adj;
        for (int c=0;c<C_;c++){
            float sg = 1.f / (1.f + expf(-(h1 * att_w2[c])));
            beta_out[tb*C_ + c] = 0.5f + 0.45f*sg;
        }
    }
}

// ---------------- K3: depthwise conv + sequential LIF scan (unchanged) ----------------
__device__ __forceinline__ void gload16(const float* src, float* lds_dst){
    __builtin_amdgcn_global_load_lds(
        (const __attribute__((address_space(1))) unsigned int*)src,
        (__attribute__((address_space(3))) unsigned int*)lds_dst, 16, 0, 0);
}

__device__ __forceinline__ float fast_atan(float x){
    float ax = fabsf(x);
    bool inv = ax > 1.f;
    float z  = inv ? __builtin_amdgcn_rcpf(ax) : ax;
    float z2 = z*z;
    float p = -0.0117212f;
    p = fmaf(p, z2,  0.05265332f);
    p = fmaf(p, z2, -0.11643287f);
    p = fmaf(p, z2,  0.19354346f);
    p = fmaf(p, z2, -0.33262347f);
    p = fmaf(p, z2,  0.99997726f);
    p = p * z;
    float r = inv ? (1.57079632679f - p) : p;
    return copysignf(r, x);
}

#define SROWS 10   // staged rows: h0-1 .. h0+8

__global__ __launch_bounds__(256, 8) void lif_kernel(
    const float* __restrict__ events,
    const float* __restrict__ conv_w,   // (C,1,3,3)
    const float* __restrict__ beta,     // [T*B*C]
    const float* __restrict__ thr,      // [T*B]
    const float* __restrict__ zeropad,  // >=16B of zeros
    float* __restrict__ out)
{
    int bid  = blockIdx.x;
    int hblk = bid & 15;                // 16 row-blocks of 8 rows
    int bc   = bid >> 4;                // 0..127
    int b = bc >> 3, c = bc & 7;
    int h0 = hblk * 8;
    int tid = threadIdx.x;
    int wv  = tid >> 6;                 // wave id 0..3

    float wk[9];
    #pragma unroll
    for (int k=0;k<9;k++) wk[k] = conv_w[c*9 + k];

    __shared__ float lds[2][SROWS*W_];  // 2 x 10 x 128 floats = 10 KiB

    int idxA = tid,        rowA = idxA >> 5, colA = (idxA & 31) * 4;
    int idxB = 256 + tid,  rowB = idxB >> 5, colB = (idxB & 31) * 4;
    int ghA = h0 - 1 + rowA;
    int ghB = h0 - 1 + rowB;
    bool okA = (ghA >= 0) && (ghA < H_);
    bool okB = (ghB >= 0) && (ghB < H_);
    const float* baseFrame = events + ((size_t)(b * C_) + c) * HW_;
    const float* srcA0 = okA ? (baseFrame + ghA*W_ + colA) : zeropad;
    const float* srcB0 = okB ? (baseFrame + ghB*W_ + colB) : zeropad;
    const size_t tstep = (size_t)B_ * CHW_;
    size_t stepA = okA ? tstep : 0;
    size_t stepB = okB ? tstep : 0;

    int w  = tid & 127;
    int rg = tid >> 7;
    int rbase = rg * 4;
    int wl = (w > 0)    ? w-1 : 0;
    int wr = (w < W_-1) ? w+1 : W_-1;
    bool hasL = (w > 0), hasR = (w < W_-1);

    float v[4];
    #pragma unroll
    for (int i=0;i<4;i++) v[i] = 0.f;

    gload16(srcA0, &lds[0][wv*256]);
    if (wv == 0) gload16(srcB0, &lds[0][1024]);

    const float* bp = beta + (b*C_ + c);
    const float* tp = thr + b;
    float bv = bp[0];
    float th = tp[0];

    for (int t = 0; t < T_; ++t){
        int cur = t & 1, nxt = cur ^ 1;
        __syncthreads();

        if (t + 1 < T_){
            gload16(srcA0 + (size_t)(t+1)*stepA, &lds[nxt][wv*256]);
            if (wv == 0) gload16(srcB0 + (size_t)(t+1)*stepB, &lds[nxt][1024]);
        }
        float bvn = (t+1 < T_) ? bp[(size_t)(t+1)*B_*C_] : 0.f;
        float thn = (t+1 < T_) ? tp[(size_t)(t+1)*B_]    : 0.f;

        const float* L = &lds[cur][0];
        float omb = 1.f - bv;
        float* op = out + ((size_t)(t*B_+b)*C_ + c)*HW_ + h0*W_;

        const float* row0 = L + rbase*W_;
        const float* row1 = row0 + W_;
        float la = hasL ? row0[wl] : 0.f;  float ma = row0[w];  float ra = hasR ? row0[wr] : 0.f;
        float lb = hasL ? row1[wl] : 0.f;  float mb = row1[w];  float rb = hasR ? row1[wr] : 0.f;

        #pragma unroll
        for (int i=0;i<4;i++){
            const float* rowc = L + (rbase+2+i)*W_;
            float lc = hasL ? rowc[wl] : 0.f;
            float mc = rowc[w];
            float rc = hasR ? rowc[wr] : 0.f;
            float wi = wk[0]*la + wk[1]*ma + wk[2]*ra
                     + wk[3]*lb + wk[4]*mb + wk[5]*rb
                     + wk[6]*lc + wk[7]*mc + wk[8]*rc;
            float vv = fmaf(bv, v[i], omb*wi);
            float sp = fast_atan(2.f*(vv - th))*0.5f + 0.5f;
            op[(rbase+i)*W_ + w] = mb * sp;
            v[i] = (1.f - sp) * vv;
            la=lb; ma=mb; ra=rb; lb=lc; mb=mc; rb=rc;
        }
        bv = bvn; th = thn;
    }
}

extern "C" void kernel_launch(void* const* d_in, const int* in_sizes, int n_in,
                              void* d_out, int out_size, void* d_ws, size_t ws_size,
                              hipStream_t stream)
{
    const float* events = (const float*)d_in[0];
    const float* conv_w = (const float*)d_in[1];
    const float* att_w1 = (const float*)d_in[2];
    const float* att_w2 = (const float*)d_in[3];
    const float* dwp    = (const float*)d_in[4];
    const float* twp    = (const float*)d_in[5];
    const float* mwp    = (const float*)d_in[6];
    float* out = (float*)d_out;

    float* ws       = (float*)d_ws;
    float* partials = ws;                              // 256*8*19 floats
    float* beta     = ws + (size_t)T_*B_*NSLICE*NV;
    float* thr      = beta + (size_t)T_*B_*C_;
    float* zeropad  = thr + T_*B_;

    stats_kernel  <<<T_*B_*NSLICE, 256, 0, stream>>>(events, partials);
    combine_kernel<<<T_*B_,        64,  0, stream>>>(partials, att_w1, att_w2,
                                                     dwp, twp, mwp, beta, thr, zeropad);
    lif_kernel    <<<B_*C_*16,     256, 0, stream>>>(events, conv_w, beta, thr, zeropad, out);
}